// Round 19
// baseline (319.253 us; speedup 1.0000x reference)
//
#include <hip/hip_runtime.h>
#include <hip/hip_bf16.h>

#define N 8192
#define DIN 128
#define DHID 256
#define DOUT 64
#define LDP 72   // outmm staging LDS row stride (ushorts)

typedef __attribute__((ext_vector_type(8))) short short8;
typedef __attribute__((ext_vector_type(8))) unsigned short u16x8;
typedef __attribute__((ext_vector_type(4))) float f32x4;
typedef __attribute__((ext_vector_type(2))) float f32x2;

typedef __attribute__((address_space(1))) const unsigned int GlbU32;
typedef __attribute__((address_space(3))) unsigned int LdsU32;

__device__ inline void gload16(const void* g, void* l) {
  __builtin_amdgcn_global_load_lds((GlbU32*)g, (LdsU32*)l, 16, 0, 0);
}

// lgkmcnt-only barrier: LDS ordering without draining vmcnt (global stores keep flying)
#define LGKM_BAR()                                            \
  do {                                                        \
    asm volatile("s_waitcnt lgkmcnt(0)" ::: "memory");        \
    __builtin_amdgcn_sched_barrier(0);                        \
    __builtin_amdgcn_s_barrier();                             \
    __builtin_amdgcn_sched_barrier(0);                        \
  } while (0)

__device__ inline unsigned short f2bf(float x) {
  unsigned u = __float_as_uint(x);
  u += 0x7FFF + ((u >> 16) & 1);   // RNE
  return (unsigned short)(u >> 16);
}
__device__ inline float bf2f(unsigned short u) {
  return __uint_as_float(((unsigned)u) << 16);
}
__device__ inline float sig_clip(float x) {
  float s = 1.0f / (1.0f + __expf(-x));
  return fmaxf(s, 0.1f);
}

// ---------------- K1: BatchNorm statistics ----------------
__global__ void bn_stats(const float* __restrict__ H, const float* __restrict__ bnw,
                         const float* __restrict__ bnb, float* __restrict__ scale,
                         float* __restrict__ shift) {
  int f = blockIdx.x;
  int t = threadIdx.x;
  float s = 0.f, sq = 0.f;
  for (int r = t; r < N; r += 256) {
    float v = H[(size_t)r * DIN + f];
    s += v; sq += v * v;
  }
  __shared__ float ss[256], s2[256];
  ss[t] = s; s2[t] = sq;
  __syncthreads();
  for (int o = 128; o > 0; o >>= 1) {
    if (t < o) { ss[t] += ss[t + o]; s2[t] += s2[t + o]; }
    __syncthreads();
  }
  if (t == 0) {
    float mean = ss[0] * (1.0f / N);
    float var = s2[0] * (1.0f / N) - mean * mean;
    float sc = rsqrtf(var + 1e-5f) * bnw[f];
    scale[f] = sc;
    shift[f] = bnb[f] - mean * sc;
  }
}

// ---------------- K2: Hn -> Hx bf16 [N,256], M2T bf16 [64][N] ----------------
__global__ __launch_bounds__(256) void proj(const float* __restrict__ H,
                     const float* __restrict__ scale, const float* __restrict__ shift,
                     const float* __restrict__ Wt, const float* __restrict__ bt,
                     const float* __restrict__ Wo, const float* __restrict__ bo,
                     unsigned short* __restrict__ Hx, unsigned short* __restrict__ M2T) {
  __shared__ float hn[8][DIN];
  int i0 = blockIdx.x * 8;
  int t = threadIdx.x;
  #pragma unroll
  for (int rep = 0; rep < 4; ++rep) {
    int idx = rep * 256 + t;
    int r = idx >> 7, c = idx & 127;
    float h = H[(size_t)(i0 + r) * DIN + c];
    hn[r][c] = fmaf(h, scale[c], shift[c]);
  }
  __syncthreads();
  {
    int c = t;
    float acc[8];
    float b = bt[c];
    #pragma unroll
    for (int r = 0; r < 8; ++r) acc[r] = b;
    for (int k = 0; k < DIN; ++k) {
      float w = Wt[k * DHID + c];
      #pragma unroll
      for (int r = 0; r < 8; ++r) acc[r] = fmaf(hn[r][k], w, acc[r]);
    }
    #pragma unroll
    for (int r = 0; r < 8; ++r) Hx[(size_t)(i0 + r) * DHID + c] = f2bf(acc[r]);
  }
  if (t < DOUT) {
    int c = t;
    float acc[8];
    float b = bo[c];
    #pragma unroll
    for (int r = 0; r < 8; ++r) acc[r] = b;
    for (int k = 0; k < DIN; ++k) {
      float w = Wo[k * DOUT + c];
      #pragma unroll
      for (int r = 0; r < 8; ++r) acc[r] = fmaf(hn[r][k], w, acc[r]);
    }
    u16x8 v;
    #pragma unroll
    for (int r = 0; r < 8; ++r) v[r] = f2bf(acc[r]);
    *(u16x8*)&M2T[(size_t)c * N + i0] = v;
  }
}

// ---------------- K3: smat — symmetric single pass, 2-PHASE staging (2 drains) ----------------
// la/lb hold one K-half [2][128][64] each (16384 ushorts). Phase h stages
// c4 = 2h,2h+1 (32 wave-chunks of 8 rows), then one __syncthreads, then MFMA.
// Masks loaded+balloted in phase 0 (latency folded into drain #1).
// V-tile reuses lb [128][128] with XOR group-swizzle.
__global__ __launch_bounds__(256) void smat(const unsigned short* __restrict__ Hx,
                     const float* __restrict__ A,
                     float* __restrict__ rowsum,
                     unsigned short* __restrict__ Vout) {
  int jt = blockIdx.x, it = blockIdx.y;
  if (jt < it) return;
  __shared__ unsigned short la[16384];        // current K-half of i-tile: [2][128][64]
  __shared__ unsigned short lb[16384];        // ditto j-tile; later V [128][128] swizzled
  __shared__ unsigned mbt32[128][4];          // upper mask; later aliased as scs[4][128]
  __shared__ unsigned mbtT[128][4];
  float* scs = (float*)mbt32;                 // alias: lifetimes barrier-separated
  int i0 = it * 128, j0 = jt * 128;
  int t = threadIdx.x;
  int w = t >> 6, l = t & 63;
  int lr = l & 15, lg = l >> 4;
  const bool offdiag = (it != jt);

  const int srow = l >> 3;
  const int scol = ((l & 7) ^ srow) * 8;
  const int fswz = (lr & 7) * 8;

  f32x4 acc[2][8];
  f32x4 zero = {0.f, 0.f, 0.f, 0.f};
  #pragma unroll
  for (int m = 0; m < 2; ++m)
    #pragma unroll
    for (int n = 0; n < 8; ++n) acc[m][n] = zero;

  // ---- phase 0: stage c4 = 0,1 (32 wave-chunks: c4l = idx>>4, rg = idx&15) ----
  #pragma unroll
  for (int idx4 = 0; idx4 < 8; ++idx4) {
    int idx = idx4 * 4 + w;                   // 0..31
    int c4l = idx >> 4, rg = idx & 15;
    int row = rg * 8 + srow;
    gload16(&Hx[(size_t)(i0 + row) * DHID + c4l * 64 + scol], &la[c4l * 8192 + rg * 512]);
    gload16(&Hx[(size_t)(j0 + row) * DHID + c4l * 64 + scol], &lb[c4l * 8192 + rg * 512]);
  }
  // ---- all mask loads + wave-local ballots (latency rides under drain #1) ----
  #pragma unroll
  for (int g = 0; g < 4; ++g) {
    const int rbase = w * 32 + g * 8;
    f32x2 au[8];
    #pragma unroll
    for (int rr = 0; rr < 8; ++rr)
      au[rr] = *(const f32x2*)&A[(size_t)(i0 + rbase + rr) * N + j0 + 2 * l];
    #pragma unroll
    for (int rr = 0; rr < 8; ++rr) {
      unsigned long long be = __ballot(au[rr][0] > 0.f);
      unsigned long long bo = __ballot(au[rr][1] > 0.f);
      if (l == 0) {
        mbt32[rbase + rr][0] = (unsigned)be;
        mbt32[rbase + rr][1] = (unsigned)(be >> 32);
        mbt32[rbase + rr][2] = (unsigned)bo;
        mbt32[rbase + rr][3] = (unsigned)(bo >> 32);
      }
    }
  }
  if (offdiag) {
    #pragma unroll
    for (int g = 0; g < 4; ++g) {
      const int rbase = w * 32 + g * 8;
      f32x2 al[8];
      #pragma unroll
      for (int rr = 0; rr < 8; ++rr)
        al[rr] = *(const f32x2*)&A[(size_t)(j0 + rbase + rr) * N + i0 + 2 * l];
      #pragma unroll
      for (int rr = 0; rr < 8; ++rr) {
        unsigned long long be = __ballot(al[rr][0] > 0.f);
        unsigned long long bo = __ballot(al[rr][1] > 0.f);
        if (l == 0) {
          mbtT[rbase + rr][0] = (unsigned)be;
          mbtT[rbase + rr][1] = (unsigned)(be >> 32);
          mbtT[rbase + rr][2] = (unsigned)bo;
          mbtT[rbase + rr][3] = (unsigned)(bo >> 32);
        }
      }
    }
  }
  __syncthreads();   // drain #1: staging half 0 + mask ds_writes visible

  // ---- MFMA half 0 (c4 = 0,1) ----
  #pragma unroll
  for (int c4l = 0; c4l < 2; ++c4l) {
    #pragma unroll
    for (int kk = 0; kk < 2; ++kk) {
      int c = (kk * 32 + lg * 8) ^ fswz;
      short8 af[2], bf[8];
      #pragma unroll
      for (int m = 0; m < 2; ++m)
        af[m] = *(const short8*)&la[c4l * 8192 + (w * 32 + m * 16 + lr) * 64 + c];
      #pragma unroll
      for (int n = 0; n < 8; ++n)
        bf[n] = *(const short8*)&lb[c4l * 8192 + (n * 16 + lr) * 64 + c];
      #pragma unroll
      for (int m = 0; m < 2; ++m)
        #pragma unroll
        for (int n = 0; n < 8; ++n)
          acc[m][n] = __builtin_amdgcn_mfma_f32_16x16x32_bf16(af[m], bf[n], acc[m][n], 0, 0, 0);
    }
  }
  LGKM_BAR();        // all waves' half-0 ds_reads retired

  // ---- phase 1: stage c4 = 2,3 ----
  #pragma unroll
  for (int idx4 = 0; idx4 < 8; ++idx4) {
    int idx = idx4 * 4 + w;
    int c4l = idx >> 4, rg = idx & 15;
    int row = rg * 8 + srow;
    gload16(&Hx[(size_t)(i0 + row) * DHID + (2 + c4l) * 64 + scol], &la[c4l * 8192 + rg * 512]);
    gload16(&Hx[(size_t)(j0 + row) * DHID + (2 + c4l) * 64 + scol], &lb[c4l * 8192 + rg * 512]);
  }
  __syncthreads();   // drain #2

  // ---- MFMA half 1 (c4 = 2,3) ----
  #pragma unroll
  for (int c4l = 0; c4l < 2; ++c4l) {
    #pragma unroll
    for (int kk = 0; kk < 2; ++kk) {
      int c = (kk * 32 + lg * 8) ^ fswz;
      short8 af[2], bf[8];
      #pragma unroll
      for (int m = 0; m < 2; ++m)
        af[m] = *(const short8*)&la[c4l * 8192 + (w * 32 + m * 16 + lr) * 64 + c];
      #pragma unroll
      for (int n = 0; n < 8; ++n)
        bf[n] = *(const short8*)&lb[c4l * 8192 + (n * 16 + lr) * 64 + c];
      #pragma unroll
      for (int m = 0; m < 2; ++m)
        #pragma unroll
        for (int n = 0; n < 8; ++n)
          acc[m][n] = __builtin_amdgcn_mfma_f32_16x16x32_bf16(af[m], bf[n], acc[m][n], 0, 0, 0);
    }
  }

  LGKM_BAR();  // MFMA ds_reads retired; lb becomes the V tile (XOR-swizzled [128][128])

  // ---- upper tile: s = sig_clip(acc) cached; v_up = s*m_up (+I), row sums ----
  // mask decode: col c = n*16+lr -> word (lr&1)*2 + (n>>2), bit (n&3)*8 + (lr>>1)
  #pragma unroll
  for (int m = 0; m < 2; ++m) {
    #pragma unroll
    for (int r = 0; r < 4; ++r) {
      int rl = w * 32 + m * 16 + lg * 4 + r;
      int gi = i0 + rl;
      unsigned w0 = mbt32[rl][(lr & 1) * 2];
      unsigned w1 = mbt32[rl][(lr & 1) * 2 + 1];
      float part = 0.f;
      int rsw = (rl & 7) << 3;
      #pragma unroll
      for (int n = 0; n < 8; ++n) {
        int gj = j0 + n * 16 + lr;
        float s = sig_clip(acc[m][n][r]);
        acc[m][n][r] = s;                       // cache for lower pass (no 2nd exp)
        unsigned mwv = (n < 4) ? w0 : w1;
        float ms = ((mwv >> ((n & 3) * 8 + (lr >> 1))) & 1u) ? 1.f : 0.f;
        float v = s * ms + (gi == gj ? 1.f : 0.f);
        part += v;
        lb[rl * 128 + ((n * 16 + lr) ^ rsw)] = f2bf(v);
      }
      part += __shfl_xor(part, 1);
      part += __shfl_xor(part, 2);
      part += __shfl_xor(part, 4);
      part += __shfl_xor(part, 8);
      if (lr == 0) atomicAdd(&rowsum[gi], part);
    }
  }

  LGKM_BAR();     // V tile visible; no vmem drain; mbt32 reads all retired
  #pragma unroll
  for (int pass = 0; pass < 8; ++pass) {
    int row = pass * 16 + (t >> 4);
    int cc = (t & 15) * 8;
    u16x8 vv = *(const u16x8*)&lb[row * 128 + (cc ^ ((row & 7) << 3))];
    *(u16x8*)&Vout[(size_t)(i0 + row) * N + j0 + cc] = vv;
  }

  // ---- lower (transposed) tile: v_lo = s*m_lo, column sums -> rowsum[j-rows] ----
  // mask decode: col rl -> word (r&1)*2 + (w>>1), bit (w&1)*16 + m*8 + lg*2 + (r>>1)
  if (offdiag) {
    LGKM_BAR();   // upper store pass's LDS reads retired; stores keep flying
    float p[8];
    #pragma unroll
    for (int n = 0; n < 8; ++n) p[n] = 0.f;
    #pragma unroll
    for (int m = 0; m < 2; ++m) {
      #pragma unroll
      for (int r = 0; r < 4; ++r) {
        int rl = w * 32 + m * 16 + lg * 4 + r;
        int wi = (r & 1) * 2 + (w >> 1);
        int bitp = (w & 1) * 16 + m * 8 + lg * 2 + (r >> 1);
        #pragma unroll
        for (int n = 0; n < 8; ++n) {
          int c = n * 16 + lr;                       // j-row within tile
          float ms = ((mbtT[c][wi] >> bitp) & 1u) ? 1.f : 0.f;
          float v = acc[m][n][r] * ms;               // s already cached — no exp
          p[n] += v;
          lb[c * 128 + (rl ^ ((c & 7) << 3))] = f2bf(v);  // transposed, swizzled
        }
      }
    }
    #pragma unroll
    for (int n = 0; n < 8; ++n) {
      p[n] += __shfl_xor(p[n], 16);
      p[n] += __shfl_xor(p[n], 32);
    }
    if (lg == 0) {
      #pragma unroll
      for (int n = 0; n < 8; ++n) scs[w * 128 + n * 16 + lr] = p[n];  // aliased mbt32
    }
    LGKM_BAR();   // transposed tile + scs visible
    if (t < 128) {
      float cs = scs[0 * 128 + t] + scs[1 * 128 + t] + scs[2 * 128 + t] + scs[3 * 128 + t];
      atomicAdd(&rowsum[j0 + t], cs);
    }
    #pragma unroll
    for (int pass = 0; pass < 8; ++pass) {
      int row = pass * 16 + (t >> 4);
      int cc = (t & 15) * 8;
      u16x8 vv = *(const u16x8*)&lb[row * 128 + (cc ^ ((row & 7) << 3))];
      *(u16x8*)&Vout[(size_t)(j0 + row) * N + i0 + cc] = vv;
    }
  }
}

// ---------------- K3b: d = rsqrt(rowsum), in place ----------------
__global__ void dfin(float* rs) {
  int i = blockIdx.x * 256 + threadIdx.x;
  if (i < N) rs[i] = rsqrtf(rs[i]);
}

// ---------------- K4: outmm — fused scale + A_hat write + out = A_hat @ M2 (R7) ----------------
__global__ __launch_bounds__(256) void outmm(const unsigned short* __restrict__ Vin,
                      const float* __restrict__ dd,
                      const unsigned short* __restrict__ M2T,
                      float* __restrict__ Ahat, float* __restrict__ out) {
  __shared__ unsigned short la[2][128 * LDP];
  int kc = blockIdx.x;   // 0..15  (j-chunk of 512)
  int it = blockIdx.y;   // 0..63  (i-tile of 128)
  int i0 = it * 128;
  int jbase = kc * 512;
  int t = threadIdx.x;
  int w = t >> 6, l = t & 63;
  int lr = l & 15, lg = l >> 4;

  f32x4 acc[2][4];
  f32x4 zero = {0.f, 0.f, 0.f, 0.f};
  #pragma unroll
  for (int m = 0; m < 2; ++m)
    #pragma unroll
    for (int n = 0; n < 4; ++n) acc[m][n] = zero;

  const unsigned short* V = (const unsigned short*)Vin;
  const int row8 = t >> 3;      // 0..31
  const int cc8 = (t & 7) * 8;  // 0..56

  float di[4];
  #pragma unroll
  for (int rep = 0; rep < 4; ++rep) di[rep] = dd[i0 + rep * 32 + row8];

  u16x8 u[2][4];
  #pragma unroll
  for (int rep = 0; rep < 4; ++rep)
    u[0][rep] = *(const u16x8*)&V[(size_t)(i0 + rep * 32 + row8) * N + jbase + cc8];

  #pragma unroll
  for (int s = 0; s < 8; ++s) {
    const int cur = s & 1;
    const int j0 = jbase + s * 64;
    if (s < 7) {
      #pragma unroll
      for (int rep = 0; rep < 4; ++rep)
        u[cur ^ 1][rep] = *(const u16x8*)&V[(size_t)(i0 + rep * 32 + row8) * N + j0 + 64 + cc8];
    }
    short8 bfr[2][4];
    #pragma unroll
    for (int kk = 0; kk < 2; ++kk)
      #pragma unroll
      for (int n = 0; n < 4; ++n)
        bfr[kk][n] = *(const short8*)&M2T[(size_t)(n * 16 + lr) * N + j0 + kk * 32 + lg * 8];
    f32x4 dj0 = *(const f32x4*)&dd[j0 + cc8];
    f32x4 dj1 = *(const f32x4*)&dd[j0 + cc8 + 4];
    #pragma unroll
    for (int rep = 0; rep < 4; ++rep) {
      int row = rep * 32 + row8;
      size_t idx = (size_t)(i0 + row) * N + j0 + cc8;
      f32x4 s0, s1;
      s0[0] = bf2f(u[cur][rep][0]) * di[rep] * dj0[0];
      s0[1] = bf2f(u[cur][rep][1]) * di[rep] * dj0[1];
      s0[2] = bf2f(u[cur][rep][2]) * di[rep] * dj0[2];
      s0[3] = bf2f(u[cur][rep][3]) * di[rep] * dj0[3];
      s1[0] = bf2f(u[cur][rep][4]) * di[rep] * dj1[0];
      s1[1] = bf2f(u[cur][rep][5]) * di[rep] * dj1[1];
      s1[2] = bf2f(u[cur][rep][6]) * di[rep] * dj1[2];
      s1[3] = bf2f(u[cur][rep][7]) * di[rep] * dj1[3];
      *(f32x4*)&Ahat[idx] = s0;
      *(f32x4*)&Ahat[idx + 4] = s1;
      u16x8 b;
      b[0] = f2bf(s0[0]); b[1] = f2bf(s0[1]); b[2] = f2bf(s0[2]); b[3] = f2bf(s0[3]);
      b[4] = f2bf(s1[0]); b[5] = f2bf(s1[1]); b[6] = f2bf(s1[2]); b[7] = f2bf(s1[3]);
      *(u16x8*)&la[cur][row * LDP + cc8] = b;
    }
    LGKM_BAR();   // ds_writes visible; Ahat stores & prefetch loads keep flying
    #pragma unroll
    for (int kk = 0; kk < 2; ++kk) {
      short8 af[2];
      #pragma unroll
      for (int m = 0; m < 2; ++m)
        af[m] = *(const short8*)&la[cur][(w * 32 + m * 16 + lr) * LDP + kk * 32 + lg * 8];
      #pragma unroll
      for (int m = 0; m < 2; ++m)
        #pragma unroll
        for (int n = 0; n < 4; ++n)
          acc[m][n] = __builtin_amdgcn_mfma_f32_16x16x32_bf16(af[m], bfr[kk][n], acc[m][n], 0, 0, 0);
    }
  }

  #pragma unroll
  for (int m = 0; m < 2; ++m)
    #pragma unroll
    for (int n = 0; n < 4; ++n)
      #pragma unroll
      for (int r = 0; r < 4; ++r) {
        int gi = i0 + w * 32 + m * 16 + lg * 4 + r;
        int gc = n * 16 + lr;
        atomicAdd(&out[(size_t)gi * DOUT + gc], acc[m][n][r]);
      }
}

// ---------------- K5: LeakyReLU on out ----------------
__global__ void leaky(float* out) {
  int i = blockIdx.x * 256 + threadIdx.x;
  if (i < N * DOUT) {
    float x = out[i];
    out[i] = x >= 0.f ? x : 0.01f * x;
  }
}

extern "C" void kernel_launch(void* const* d_in, const int* in_sizes, int n_in,
                              void* d_out, int out_size, void* d_ws, size_t ws_size,
                              hipStream_t stream) {
  const float* H   = (const float*)d_in[0];
  const float* A   = (const float*)d_in[1];
  const float* bnw = (const float*)d_in[2];
  const float* bnb = (const float*)d_in[3];
  const float* Wt  = (const float*)d_in[4];
  const float* bt  = (const float*)d_in[5];
  const float* Wo  = (const float*)d_in[6];
  const float* bo  = (const float*)d_in[7];
  float* out = (float*)d_out;
  float* Ahat = out + (size_t)N * DOUT;

  char* ws = (char*)d_ws;
  float* scale  = (float*)(ws + 0);
  float* shift  = (float*)(ws + 512);
  float* rowsum = (float*)(ws + 4096);                    // becomes d after dfin
  unsigned short* M2T = (unsigned short*)(ws + 65536);    // 1 MB slot [64][N]
  unsigned short* Hx  = (unsigned short*)(ws + 2097152);  // 4 MB slot
  unsigned short* Vbf = (unsigned short*)(ws + (size_t)(14u << 20));        // 128 MiB slot

  hipMemsetAsync(rowsum, 0, N * sizeof(float), stream);
  hipMemsetAsync(out, 0, (size_t)N * DOUT * sizeof(float), stream);

  bn_stats<<<DIN, 256, 0, stream>>>(H, bnw, bnb, scale, shift);
  proj<<<N / 8, 256, 0, stream>>>(H, scale, shift, Wt, bt, Wo, bo, Hx, M2T);
  smat<<<dim3(64, 64), 256, 0, stream>>>(Hx, A, rowsum, Vbf);
  dfin<<<N / 256, 256, 0, stream>>>(rowsum);
  outmm<<<dim3(16, 64), 256, 0, stream>>>(Vbf, rowsum, M2T, Ahat, out);
  leaky<<<(N * DOUT + 255) / 256, 256, 0, stream>>>(out);
}

// Round 20
// 309.046 us; speedup vs baseline: 1.0330x; 1.0330x over previous
//
#include <hip/hip_runtime.h>
#include <hip/hip_bf16.h>

#define N 8192
#define DIN 128
#define DHID 256
#define DOUT 64
#define LDP 72   // outmm staging LDS row stride (ushorts)
#define VP 136   // V-epilogue LDS row stride (ushorts)

typedef __attribute__((ext_vector_type(8))) short short8;
typedef __attribute__((ext_vector_type(8))) unsigned short u16x8;
typedef __attribute__((ext_vector_type(4))) float f32x4;
typedef __attribute__((ext_vector_type(2))) float f32x2;

typedef __attribute__((address_space(1))) const unsigned int GlbU32;
typedef __attribute__((address_space(3))) unsigned int LdsU32;

__device__ inline void gload16(const void* g, void* l) {
  __builtin_amdgcn_global_load_lds((GlbU32*)g, (LdsU32*)l, 16, 0, 0);
}

// lgkmcnt-only barrier: LDS ordering without draining vmcnt (global stores keep flying)
#define LGKM_BAR()                                            \
  do {                                                        \
    asm volatile("s_waitcnt lgkmcnt(0)" ::: "memory");        \
    __builtin_amdgcn_sched_barrier(0);                        \
    __builtin_amdgcn_s_barrier();                             \
    __builtin_amdgcn_sched_barrier(0);                        \
  } while (0)

__device__ inline unsigned short f2bf(float x) {
  unsigned u = __float_as_uint(x);
  u += 0x7FFF + ((u >> 16) & 1);   // RNE
  return (unsigned short)(u >> 16);
}
__device__ inline float bf2f(unsigned short u) {
  return __uint_as_float(((unsigned)u) << 16);
}
__device__ inline float sig_clip(float x) {
  float s = 1.0f / (1.0f + __expf(-x));
  return fmaxf(s, 0.1f);
}

// ---------------- K1: BatchNorm statistics ----------------
__global__ void bn_stats(const float* __restrict__ H, const float* __restrict__ bnw,
                         const float* __restrict__ bnb, float* __restrict__ scale,
                         float* __restrict__ shift) {
  int f = blockIdx.x;
  int t = threadIdx.x;
  float s = 0.f, sq = 0.f;
  for (int r = t; r < N; r += 256) {
    float v = H[(size_t)r * DIN + f];
    s += v; sq += v * v;
  }
  __shared__ float ss[256], s2[256];
  ss[t] = s; s2[t] = sq;
  __syncthreads();
  for (int o = 128; o > 0; o >>= 1) {
    if (t < o) { ss[t] += ss[t + o]; s2[t] += s2[t + o]; }
    __syncthreads();
  }
  if (t == 0) {
    float mean = ss[0] * (1.0f / N);
    float var = s2[0] * (1.0f / N) - mean * mean;
    float sc = rsqrtf(var + 1e-5f) * bnw[f];
    scale[f] = sc;
    shift[f] = bnb[f] - mean * sc;
  }
}

// ---------------- K2: Hn -> Hx bf16 [N,256], M2T bf16 [64][N] ----------------
__global__ __launch_bounds__(256) void proj(const float* __restrict__ H,
                     const float* __restrict__ scale, const float* __restrict__ shift,
                     const float* __restrict__ Wt, const float* __restrict__ bt,
                     const float* __restrict__ Wo, const float* __restrict__ bo,
                     unsigned short* __restrict__ Hx, unsigned short* __restrict__ M2T) {
  __shared__ float hn[8][DIN];
  int i0 = blockIdx.x * 8;
  int t = threadIdx.x;
  #pragma unroll
  for (int rep = 0; rep < 4; ++rep) {
    int idx = rep * 256 + t;
    int r = idx >> 7, c = idx & 127;
    float h = H[(size_t)(i0 + r) * DIN + c];
    hn[r][c] = fmaf(h, scale[c], shift[c]);
  }
  __syncthreads();
  {
    int c = t;
    float acc[8];
    float b = bt[c];
    #pragma unroll
    for (int r = 0; r < 8; ++r) acc[r] = b;
    for (int k = 0; k < DIN; ++k) {
      float w = Wt[k * DHID + c];
      #pragma unroll
      for (int r = 0; r < 8; ++r) acc[r] = fmaf(hn[r][k], w, acc[r]);
    }
    #pragma unroll
    for (int r = 0; r < 8; ++r) Hx[(size_t)(i0 + r) * DHID + c] = f2bf(acc[r]);
  }
  if (t < DOUT) {
    int c = t;
    float acc[8];
    float b = bo[c];
    #pragma unroll
    for (int r = 0; r < 8; ++r) acc[r] = b;
    for (int k = 0; k < DIN; ++k) {
      float w = Wo[k * DOUT + c];
      #pragma unroll
      for (int r = 0; r < 8; ++r) acc[r] = fmaf(hn[r][k], w, acc[r]);
    }
    u16x8 v;
    #pragma unroll
    for (int r = 0; r < 8; ++r) v[r] = f2bf(acc[r]);
    *(u16x8*)&M2T[(size_t)c * N + i0] = v;
  }
}

// ---------------- K3: smat — symmetric single pass, fused A-scan, scs aliased to mbt32 ----------------
__global__ __launch_bounds__(256) void smat(const unsigned short* __restrict__ Hx,
                     const float* __restrict__ A,
                     float* __restrict__ rowsum,
                     unsigned short* __restrict__ Vout) {
  int jt = blockIdx.x, it = blockIdx.y;
  if (jt < it) return;
  __shared__ unsigned short lsh[17408];       // staging la/lb; later the V tile [128][VP]
  __shared__ unsigned mbt32[128][4];          // upper mask; later aliased as scs[4][128]
  __shared__ unsigned mbtT[128][4];
  unsigned short* la = lsh;
  unsigned short* lb = lsh + 8192;
  float* scs = (float*)mbt32;                 // alias: safe, lifetimes barrier-separated
  int i0 = it * 128, j0 = jt * 128;
  int t = threadIdx.x;
  int w = t >> 6, l = t & 63;
  int lr = l & 15, lg = l >> 4;
  const bool offdiag = (it != jt);

  f32x4 acc[2][8];
  f32x4 zero = {0.f, 0.f, 0.f, 0.f};
  #pragma unroll
  for (int m = 0; m < 2; ++m)
    #pragma unroll
    for (int n = 0; n < 8; ++n) acc[m][n] = zero;

  const int srow = l >> 3;
  const int scol = ((l & 7) ^ srow) * 8;
  const int fswz = (lr & 7) * 8;

  for (int c4 = 0; c4 < 4; ++c4) {
    int k0 = c4 * 64;
    __syncthreads();
    #pragma unroll
    for (int rp = 0; rp < 4; ++rp) {
      int chunk = rp * 4 + w;
      int row = chunk * 8 + srow;
      gload16(&Hx[(size_t)(i0 + row) * DHID + k0 + scol], &la[chunk * 512]);
      gload16(&Hx[(size_t)(j0 + row) * DHID + k0 + scol], &lb[chunk * 512]);
    }
    // A-tile loads for this c4's 8 rows/wave (concurrent with staging; the
    // following __syncthreads drains vmcnt for both streams together)
    const int rbase = w * 32 + c4 * 8;
    f32x2 au[8], al[8];
    #pragma unroll
    for (int rr = 0; rr < 8; ++rr)
      au[rr] = *(const f32x2*)&A[(size_t)(i0 + rbase + rr) * N + j0 + 2 * l];
    if (offdiag) {
      #pragma unroll
      for (int rr = 0; rr < 8; ++rr)
        al[rr] = *(const f32x2*)&A[(size_t)(j0 + rbase + rr) * N + i0 + 2 * l];
    }
    __syncthreads();
    // ballots -> LDS bitmask (data already resident; short reg lifetime)
    #pragma unroll
    for (int rr = 0; rr < 8; ++rr) {
      unsigned long long be = __ballot(au[rr][0] > 0.f);
      unsigned long long bo = __ballot(au[rr][1] > 0.f);
      if (l == 0) {
        mbt32[rbase + rr][0] = (unsigned)be;
        mbt32[rbase + rr][1] = (unsigned)(be >> 32);
        mbt32[rbase + rr][2] = (unsigned)bo;
        mbt32[rbase + rr][3] = (unsigned)(bo >> 32);
      }
    }
    if (offdiag) {
      #pragma unroll
      for (int rr = 0; rr < 8; ++rr) {
        unsigned long long be = __ballot(al[rr][0] > 0.f);
        unsigned long long bo = __ballot(al[rr][1] > 0.f);
        if (l == 0) {
          mbtT[rbase + rr][0] = (unsigned)be;
          mbtT[rbase + rr][1] = (unsigned)(be >> 32);
          mbtT[rbase + rr][2] = (unsigned)bo;
          mbtT[rbase + rr][3] = (unsigned)(bo >> 32);
        }
      }
    }
    #pragma unroll
    for (int kk = 0; kk < 2; ++kk) {
      int c = (kk * 32 + lg * 8) ^ fswz;
      short8 af[2], bf[8];
      #pragma unroll
      for (int m = 0; m < 2; ++m)
        af[m] = *(const short8*)&la[(w * 32 + m * 16 + lr) * 64 + c];
      #pragma unroll
      for (int n = 0; n < 8; ++n)
        bf[n] = *(const short8*)&lb[(n * 16 + lr) * 64 + c];
      #pragma unroll
      for (int m = 0; m < 2; ++m)
        #pragma unroll
        for (int n = 0; n < 8; ++n)
          acc[m][n] = __builtin_amdgcn_mfma_f32_16x16x32_bf16(af[m], bf[n], acc[m][n], 0, 0, 0);
    }
  }

  LGKM_BAR();  // MFMA ds_reads + mask ds_writes retired; lsh becomes the V tile

  // ---- upper tile: s = sig_clip(acc) cached; v_up = s*m_up (+I), row sums ----
  // decode: col c = n*16+lr -> word (lr&1)*2 + (n>>2), bit (n&3)*8 + (lr>>1)
  #pragma unroll
  for (int m = 0; m < 2; ++m) {
    #pragma unroll
    for (int r = 0; r < 4; ++r) {
      int rl = w * 32 + m * 16 + lg * 4 + r;
      int gi = i0 + rl;
      unsigned w0 = mbt32[rl][(lr & 1) * 2];
      unsigned w1 = mbt32[rl][(lr & 1) * 2 + 1];
      float part = 0.f;
      #pragma unroll
      for (int n = 0; n < 8; ++n) {
        int gj = j0 + n * 16 + lr;
        float s = sig_clip(acc[m][n][r]);
        acc[m][n][r] = s;                       // cache for lower pass (no 2nd exp)
        unsigned mwv = (n < 4) ? w0 : w1;
        float ms = ((mwv >> ((n & 3) * 8 + (lr >> 1))) & 1u) ? 1.f : 0.f;
        float v = s * ms + (gi == gj ? 1.f : 0.f);
        part += v;
        lsh[rl * VP + n * 16 + lr] = f2bf(v);
      }
      part += __shfl_xor(part, 1);
      part += __shfl_xor(part, 2);
      part += __shfl_xor(part, 4);
      part += __shfl_xor(part, 8);
      if (lr == 0) atomicAdd(&rowsum[gi], part);
    }
  }

  LGKM_BAR();     // V tile visible; no vmem drain; mbt32 reads all retired
  #pragma unroll
  for (int pass = 0; pass < 8; ++pass) {
    int row = pass * 16 + (t >> 4);
    int cc = (t & 15) * 8;
    u16x8 vv = *(const u16x8*)&lsh[row * VP + cc];
    *(u16x8*)&Vout[(size_t)(i0 + row) * N + j0 + cc] = vv;
  }

  // ---- lower (transposed) tile: v_lo = s*m_lo, column sums -> rowsum[j-rows] ----
  // decode: col rl = w*32+m*16+lg*4+r -> word (r&1)*2 + (w>>1),
  //         bit (w&1)*16 + m*8 + lg*2 + (r>>1)
  if (offdiag) {
    LGKM_BAR();   // upper store pass's LDS reads retired; stores keep flying
    float p[8];
    #pragma unroll
    for (int n = 0; n < 8; ++n) p[n] = 0.f;
    #pragma unroll
    for (int m = 0; m < 2; ++m) {
      #pragma unroll
      for (int r = 0; r < 4; ++r) {
        int rl = w * 32 + m * 16 + lg * 4 + r;
        int wi = (r & 1) * 2 + (w >> 1);
        int bitp = (w & 1) * 16 + m * 8 + lg * 2 + (r >> 1);
        #pragma unroll
        for (int n = 0; n < 8; ++n) {
          int c = n * 16 + lr;                       // j-row within tile
          float ms = ((mbtT[c][wi] >> bitp) & 1u) ? 1.f : 0.f;
          float v = acc[m][n][r] * ms;               // s already cached — no exp
          p[n] += v;
          lsh[c * VP + rl] = f2bf(v);                // transposed position
        }
      }
    }
    #pragma unroll
    for (int n = 0; n < 8; ++n) {
      p[n] += __shfl_xor(p[n], 16);
      p[n] += __shfl_xor(p[n], 32);
    }
    if (lg == 0) {
      #pragma unroll
      for (int n = 0; n < 8; ++n) scs[w * 128 + n * 16 + lr] = p[n];  // aliased mbt32
    }
    LGKM_BAR();   // lsh transposed tile + scs visible
    if (t < 128) {
      float cs = scs[0 * 128 + t] + scs[1 * 128 + t] + scs[2 * 128 + t] + scs[3 * 128 + t];
      atomicAdd(&rowsum[j0 + t], cs);
    }
    #pragma unroll
    for (int pass = 0; pass < 8; ++pass) {
      int row = pass * 16 + (t >> 4);
      int cc = (t & 15) * 8;
      u16x8 vv = *(const u16x8*)&lsh[row * VP + cc];
      *(u16x8*)&Vout[(size_t)(j0 + row) * N + i0 + cc] = vv;
    }
  }
}

// ---------------- K3b: d = rsqrt(rowsum), in place ----------------
__global__ void dfin(float* rs) {
  int i = blockIdx.x * 256 + threadIdx.x;
  if (i < N) rs[i] = rsqrtf(rs[i]);
}

// ---------------- K4: outmm — fused scale + A_hat write + out = A_hat @ M2 (R7) ----------------
__global__ __launch_bounds__(256) void outmm(const unsigned short* __restrict__ Vin,
                      const float* __restrict__ dd,
                      const unsigned short* __restrict__ M2T,
                      float* __restrict__ Ahat, float* __restrict__ out) {
  __shared__ unsigned short la[2][128 * LDP];
  int kc = blockIdx.x;   // 0..15  (j-chunk of 512)
  int it = blockIdx.y;   // 0..63  (i-tile of 128)
  int i0 = it * 128;
  int jbase = kc * 512;
  int t = threadIdx.x;
  int w = t >> 6, l = t & 63;
  int lr = l & 15, lg = l >> 4;

  f32x4 acc[2][4];
  f32x4 zero = {0.f, 0.f, 0.f, 0.f};
  #pragma unroll
  for (int m = 0; m < 2; ++m)
    #pragma unroll
    for (int n = 0; n < 4; ++n) acc[m][n] = zero;

  const unsigned short* V = (const unsigned short*)Vin;
  const int row8 = t >> 3;      // 0..31
  const int cc8 = (t & 7) * 8;  // 0..56

  float di[4];
  #pragma unroll
  for (int rep = 0; rep < 4; ++rep) di[rep] = dd[i0 + rep * 32 + row8];

  u16x8 u[2][4];
  #pragma unroll
  for (int rep = 0; rep < 4; ++rep)
    u[0][rep] = *(const u16x8*)&V[(size_t)(i0 + rep * 32 + row8) * N + jbase + cc8];

  #pragma unroll
  for (int s = 0; s < 8; ++s) {
    const int cur = s & 1;
    const int j0 = jbase + s * 64;
    if (s < 7) {
      #pragma unroll
      for (int rep = 0; rep < 4; ++rep)
        u[cur ^ 1][rep] = *(const u16x8*)&V[(size_t)(i0 + rep * 32 + row8) * N + j0 + 64 + cc8];
    }
    short8 bfr[2][4];
    #pragma unroll
    for (int kk = 0; kk < 2; ++kk)
      #pragma unroll
      for (int n = 0; n < 4; ++n)
        bfr[kk][n] = *(const short8*)&M2T[(size_t)(n * 16 + lr) * N + j0 + kk * 32 + lg * 8];
    f32x4 dj0 = *(const f32x4*)&dd[j0 + cc8];
    f32x4 dj1 = *(const f32x4*)&dd[j0 + cc8 + 4];
    #pragma unroll
    for (int rep = 0; rep < 4; ++rep) {
      int row = rep * 32 + row8;
      size_t idx = (size_t)(i0 + row) * N + j0 + cc8;
      f32x4 s0, s1;
      s0[0] = bf2f(u[cur][rep][0]) * di[rep] * dj0[0];
      s0[1] = bf2f(u[cur][rep][1]) * di[rep] * dj0[1];
      s0[2] = bf2f(u[cur][rep][2]) * di[rep] * dj0[2];
      s0[3] = bf2f(u[cur][rep][3]) * di[rep] * dj0[3];
      s1[0] = bf2f(u[cur][rep][4]) * di[rep] * dj1[0];
      s1[1] = bf2f(u[cur][rep][5]) * di[rep] * dj1[1];
      s1[2] = bf2f(u[cur][rep][6]) * di[rep] * dj1[2];
      s1[3] = bf2f(u[cur][rep][7]) * di[rep] * dj1[3];
      *(f32x4*)&Ahat[idx] = s0;
      *(f32x4*)&Ahat[idx + 4] = s1;
      u16x8 b;
      b[0] = f2bf(s0[0]); b[1] = f2bf(s0[1]); b[2] = f2bf(s0[2]); b[3] = f2bf(s0[3]);
      b[4] = f2bf(s1[0]); b[5] = f2bf(s1[1]); b[6] = f2bf(s1[2]); b[7] = f2bf(s1[3]);
      *(u16x8*)&la[cur][row * LDP + cc8] = b;
    }
    LGKM_BAR();   // ds_writes visible; Ahat stores & prefetch loads keep flying
    #pragma unroll
    for (int kk = 0; kk < 2; ++kk) {
      short8 af[2];
      #pragma unroll
      for (int m = 0; m < 2; ++m)
        af[m] = *(const short8*)&la[cur][(w * 32 + m * 16 + lr) * LDP + kk * 32 + lg * 8];
      #pragma unroll
      for (int m = 0; m < 2; ++m)
        #pragma unroll
        for (int n = 0; n < 4; ++n)
          acc[m][n] = __builtin_amdgcn_mfma_f32_16x16x32_bf16(af[m], bfr[kk][n], acc[m][n], 0, 0, 0);
    }
  }

  #pragma unroll
  for (int m = 0; m < 2; ++m)
    #pragma unroll
    for (int n = 0; n < 4; ++n)
      #pragma unroll
      for (int r = 0; r < 4; ++r) {
        int gi = i0 + w * 32 + m * 16 + lg * 4 + r;
        int gc = n * 16 + lr;
        atomicAdd(&out[(size_t)gi * DOUT + gc], acc[m][n][r]);
      }
}

// ---------------- K5: LeakyReLU on out ----------------
__global__ void leaky(float* out) {
  int i = blockIdx.x * 256 + threadIdx.x;
  if (i < N * DOUT) {
    float x = out[i];
    out[i] = x >= 0.f ? x : 0.01f * x;
  }
}

extern "C" void kernel_launch(void* const* d_in, const int* in_sizes, int n_in,
                              void* d_out, int out_size, void* d_ws, size_t ws_size,
                              hipStream_t stream) {
  const float* H   = (const float*)d_in[0];
  const float* A   = (const float*)d_in[1];
  const float* bnw = (const float*)d_in[2];
  const float* bnb = (const float*)d_in[3];
  const float* Wt  = (const float*)d_in[4];
  const float* bt  = (const float*)d_in[5];
  const float* Wo  = (const float*)d_in[6];
  const float* bo  = (const float*)d_in[7];
  float* out = (float*)d_out;
  float* Ahat = out + (size_t)N * DOUT;

  char* ws = (char*)d_ws;
  float* scale  = (float*)(ws + 0);
  float* shift  = (float*)(ws + 512);
  float* rowsum = (float*)(ws + 4096);                    // becomes d after dfin
  unsigned short* M2T = (unsigned short*)(ws + 65536);    // 1 MB slot [64][N]
  unsigned short* Hx  = (unsigned short*)(ws + 2097152);  // 4 MB slot
  unsigned short* Vbf = (unsigned short*)(ws + (size_t)(14u << 20));        // 128 MiB slot

  hipMemsetAsync(rowsum, 0, N * sizeof(float), stream);
  hipMemsetAsync(out, 0, (size_t)N * DOUT * sizeof(float), stream);

  bn_stats<<<DIN, 256, 0, stream>>>(H, bnw, bnb, scale, shift);
  proj<<<N / 8, 256, 0, stream>>>(H, scale, shift, Wt, bt, Wo, bo, Hx, M2T);
  smat<<<dim3(64, 64), 256, 0, stream>>>(Hx, A, rowsum, Vbf);
  dfin<<<N / 256, 256, 0, stream>>>(rowsum);
  outmm<<<dim3(16, 64), 256, 0, stream>>>(Vbf, rowsum, M2T, Ahat, out);
  leaky<<<(N * DOUT + 255) / 256, 256, 0, stream>>>(out);
}